// Round 2
// baseline (353.641 us; speedup 1.0000x reference)
//
#include <hip/hip_runtime.h>
#include <hip/hip_bf16.h>
#include <stdint.h>

#define NTOK 8192
#define DIM  512
#define QKVW 1536

typedef __attribute__((ext_vector_type(8))) short bf16x8;
typedef __attribute__((ext_vector_type(4))) float f32x4;

static __device__ __forceinline__ unsigned short f2b(float f) {
    union { float f; unsigned int u; } v; v.f = f;
    unsigned int r = v.u + 0x7fffu + ((v.u >> 16) & 1u);
    return (unsigned short)(r >> 16);
}

static __device__ __forceinline__ void gld_lds16(const void* g, void* l) {
    __builtin_amdgcn_global_load_lds(
        (__attribute__((address_space(1))) void*)(uintptr_t)g,
        (__attribute__((address_space(3))) void*)(uintptr_t)l,
        16, 0, 0);
}

#define SBAR() do { __builtin_amdgcn_sched_barrier(0); __builtin_amdgcn_s_barrier(); __builtin_amdgcn_sched_barrier(0); } while (0)

template <int N> static __device__ __forceinline__ void vmw() {
    if constexpr (N == 8)      asm volatile("s_waitcnt vmcnt(8)" ::: "memory");
    else if constexpr (N == 6) asm volatile("s_waitcnt vmcnt(6)" ::: "memory");
    else if constexpr (N == 4) asm volatile("s_waitcnt vmcnt(4)" ::: "memory");
    else if constexpr (N == 3) asm volatile("s_waitcnt vmcnt(3)" ::: "memory");
    else                       asm volatile("s_waitcnt vmcnt(0)" ::: "memory");
    __builtin_amdgcn_sched_barrier(0);
}

// ---------------- converts ----------------

__global__ void f2b_kernel(const float* __restrict__ src, unsigned short* __restrict__ dst, int n4) {
    int i = blockIdx.x * blockDim.x + threadIdx.x;
    if (i < n4) {
        float4 f = ((const float4*)src)[i];
        ushort4 o;
        o.x = f2b(f.x); o.y = f2b(f.y); o.z = f2b(f.z); o.w = f2b(f.w);
        ((ushort4*)dst)[i] = o;
    }
}

__global__ void bias_concat(const float* __restrict__ bq, const float* __restrict__ bk,
                            const float* __restrict__ bv, float* __restrict__ bc) {
    int i = blockIdx.x * blockDim.x + threadIdx.x;
    if (i < 512)       bc[i] = bq[i];
    else if (i < 1024) bc[i] = bk[i - 512];
    else if (i < 1536) bc[i] = bv[i - 1024];
}

// ---------------- V transpose ----------------
__global__ void transpose_v(const unsigned short* __restrict__ qkv, unsigned short* __restrict__ vt) {
    __shared__ unsigned short t[64][65];
    int j0 = blockIdx.x * 64;
    int d0 = blockIdx.y * 64;
    int tid = threadIdx.x;
    int c  = tid & 63;
    int r4 = tid >> 6;
    #pragma unroll
    for (int r = r4; r < 64; r += 4)
        t[r][c] = qkv[(size_t)(j0 + r) * QKVW + 1024 + d0 + c];
    __syncthreads();
    #pragma unroll
    for (int r = r4; r < 64; r += 4)
        vt[(size_t)(d0 + r) * NTOK + j0 + c] = t[c][r];
}

// ---------------- 256-row tile GEMM, C = A * B^T ----------------
// 8 waves (2Mx4N), per-wave 128 x (NR*16) output. BK=32, 4-deep LDS ring,
// counted vmcnt (never 0 in steady state), raw s_barrier, setprio MFMA.
// LDS per buffer: A [4 kslot][256 row][16B] (16KB) + B [4][NR*64][16B].
// EPI 0: bf16 store + bias[col]            (QKV projection)
// EPI 1: bf16 store + atomic row sum-sq    (S = Q K^T)
// EPI 2: fp32 partial store (split-K by z) (O = S V)
template <int EPI, int NR>
__global__ __launch_bounds__(512, 2) void gemm256(
    const unsigned short* __restrict__ A, int lda,
    const unsigned short* __restrict__ B, int ldb,
    int Ksplit,
    void* __restrict__ Cout, int ldc,
    const float* __restrict__ bias,
    float* __restrict__ rowss) {

    constexpr int SB = 16384 + NR * 4096;   // bytes per ring buffer (A+B)
    constexpr int P  = 2 + NR / 2;          // gld_lds issues per tile per thread

    __shared__ __align__(16) char lds[SB * 4];

    const int tid = threadIdx.x;
    const int l = tid & 63, w = tid >> 6;
    const int wm = w >> 2, wn = w & 3;

    // bijective XCD swizzle over the x*y grid (x*y divisible by 8 for all launches)
    const int gx = gridDim.x;
    const int bid = blockIdx.y * gx + blockIdx.x;
    const int cpx = (gridDim.y * gx) >> 3;
    const int swz = (bid & 7) * cpx + (bid >> 3);
    const int bn = swz % gx, bm = swz / gx;

    const int kt0 = blockIdx.z * Ksplit;
    const int NT = Ksplit >> 5;

    // per-thread staging source pointers (pre-permuted so linear LDS dest = blocked layout)
    const unsigned short* gA0 = A + (size_t)(bm * 256 + (w & 3) * 64 + l) * lda + kt0 + (w >> 2) * 8;
    const unsigned short* gB0;
    if constexpr (NR == 4)
        gB0 = B + (size_t)(bn * 256 + (w & 3) * 64 + l) * ldb + kt0 + (w >> 2) * 8;
    else
        gB0 = B + (size_t)(bn * 128 + (w & 1) * 64 + l) * ldb + kt0 + (w >> 1) * 8;

    auto STAGE = [&](int tile) {
        char* lb = lds + (tile & 3) * SB + w * 1024;
        const unsigned short* ga = gA0 + tile * 32;
        const unsigned short* gb = gB0 + tile * 32;
        gld_lds16(ga,      lb);
        gld_lds16(ga + 16, lb + 8192);
        gld_lds16(gb,      lb + 16384);
        if constexpr (NR == 4) gld_lds16(gb + 16, lb + 16384 + 8192);
    };

    f32x4 acc[8][NR] = {};

    STAGE(0); STAGE(1); STAGE(2);
    vmw<2 * P>();
    SBAR();

    const int lrdA = (l >> 4) * 4096 + (l & 15) * 16 + wm * 2048;
    const int lrdB = 16384 + (l >> 4) * (NR * 1024) + (l & 15) * 16 + wn * (NR * 256);

    for (int t = 0; t < NT; ++t) {
        if (t + 3 < NT) STAGE(t + 3);
        __builtin_amdgcn_s_setprio(1);
        const char* lb = lds + (t & 3) * SB;
        bf16x8 af[8], bf[NR];
        #pragma unroll
        for (int m = 0; m < 8; ++m) af[m] = *(const bf16x8*)(lb + lrdA + m * 256);
        #pragma unroll
        for (int n = 0; n < NR; ++n) bf[n] = *(const bf16x8*)(lb + lrdB + n * 256);
        #pragma unroll
        for (int m = 0; m < 8; ++m)
            #pragma unroll
            for (int n = 0; n < NR; ++n)
                acc[m][n] = __builtin_amdgcn_mfma_f32_16x16x32_bf16(af[m], bf[n], acc[m][n], 0, 0, 0);
        __builtin_amdgcn_s_setprio(0);
        if (t + 3 < NT)      vmw<2 * P>();
        else if (t + 2 < NT) vmw<P>();
        else if (t + 1 < NT) vmw<0>();
        SBAR();
    }

    const int rbase = bm * 256 + wm * 128 + (l >> 4) * 4;
    const int cbase = bn * (NR * 64) + wn * (NR * 16) + (l & 15);

    if constexpr (EPI == 0) {
        unsigned short* C = (unsigned short*)Cout;
        #pragma unroll
        for (int m = 0; m < 8; ++m)
            #pragma unroll
            for (int n = 0; n < NR; ++n)
                #pragma unroll
                for (int j = 0; j < 4; ++j) {
                    int r = rbase + m * 16 + j;
                    int c = cbase + n * 16;
                    C[(size_t)r * ldc + c] = f2b(acc[m][n][j] + bias[c]);
                }
    } else if constexpr (EPI == 1) {
        unsigned short* C = (unsigned short*)Cout;
        #pragma unroll
        for (int m = 0; m < 8; ++m)
            #pragma unroll
            for (int n = 0; n < NR; ++n)
                #pragma unroll
                for (int j = 0; j < 4; ++j) {
                    int r = rbase + m * 16 + j;
                    int c = cbase + n * 16;
                    C[(size_t)r * ldc + c] = f2b(acc[m][n][j]);
                }
        #pragma unroll
        for (int m = 0; m < 8; ++m)
            #pragma unroll
            for (int j = 0; j < 4; ++j) {
                float p = 0.f;
                #pragma unroll
                for (int n = 0; n < NR; ++n) {
                    float v = acc[m][n][j];
                    p += v * v;
                }
                p += __shfl_xor(p, 1);
                p += __shfl_xor(p, 2);
                p += __shfl_xor(p, 4);
                p += __shfl_xor(p, 8);
                if ((l & 15) == 0)
                    atomicAdd(&rowss[rbase + m * 16 + j], p);
            }
    } else {
        float* C = (float*)Cout + (size_t)blockIdx.z * (gridDim.y * 256) * ldc;
        #pragma unroll
        for (int m = 0; m < 8; ++m)
            #pragma unroll
            for (int j = 0; j < 4; ++j) {
                int r = rbase + m * 16 + j;
                #pragma unroll
                for (int n = 0; n < NR; ++n)
                    C[(size_t)r * ldc + cbase + n * 16] = acc[m][n][j];
            }
    }
}

// ---------------- split-K reduce + row-norm scale ----------------
__global__ void reduce_scale(const float* __restrict__ p, const float* __restrict__ rss,
                             float* __restrict__ out) {
    int i = blockIdx.x * blockDim.x + threadIdx.x;  // over NTOK*DIM/4
    const float4 a = ((const float4*)p)[i];
    const float4 b = ((const float4*)(p + (size_t)NTOK * DIM))[i];
    int r = (i << 2) >> 9;  // (i*4)/DIM
    float s = 1.0f / fmaxf(sqrtf(rss[r]), 1e-12f);
    float4 o;
    o.x = (a.x + b.x) * s;
    o.y = (a.y + b.y) * s;
    o.z = (a.z + b.z) * s;
    o.w = (a.w + b.w) * s;
    ((float4*)out)[i] = o;
}

extern "C" void kernel_launch(void* const* d_in, const int* in_sizes, int n_in,
                              void* d_out, int out_size, void* d_ws, size_t ws_size,
                              hipStream_t stream) {
    const float* x  = (const float*)d_in[0];
    const float* Wq = (const float*)d_in[1];
    const float* bq = (const float*)d_in[2];
    const float* Wk = (const float*)d_in[3];
    const float* bk = (const float*)d_in[4];
    const float* Wv = (const float*)d_in[5];
    const float* bv = (const float*)d_in[6];
    float* out = (float*)d_out;

    char* ws = (char*)d_ws;
    size_t off = 0;
    auto alloc = [&](size_t bytes) -> void* {
        void* p = ws + off;
        off = (off + bytes + 255) & ~(size_t)255;
        return p;
    };

    unsigned short* xb   = (unsigned short*)alloc((size_t)NTOK * DIM * 2);
    unsigned short* Wb   = (unsigned short*)alloc((size_t)QKVW * DIM * 2);
    float*          bc   = (float*)alloc(QKVW * 4);
    unsigned short* QKV  = (unsigned short*)alloc((size_t)NTOK * QKVW * 2);
    unsigned short* Vt   = (unsigned short*)alloc((size_t)DIM * NTOK * 2);
    float*          rss  = (float*)alloc(NTOK * 4);
    float*          part = (float*)alloc((size_t)2 * NTOK * DIM * 4);
    unsigned short* S    = (unsigned short*)alloc((size_t)NTOK * NTOK * 2);

    // converts
    f2b_kernel<<<(NTOK * DIM / 4 + 255) / 256, 256, 0, stream>>>(x, xb, NTOK * DIM / 4);
    f2b_kernel<<<(DIM * DIM / 4 + 255) / 256, 256, 0, stream>>>(Wq, Wb, DIM * DIM / 4);
    f2b_kernel<<<(DIM * DIM / 4 + 255) / 256, 256, 0, stream>>>(Wk, Wb + DIM * DIM, DIM * DIM / 4);
    f2b_kernel<<<(DIM * DIM / 4 + 255) / 256, 256, 0, stream>>>(Wv, Wb + 2 * DIM * DIM, DIM * DIM / 4);
    bias_concat<<<6, 256, 0, stream>>>(bq, bk, bv, bc);
    hipMemsetAsync(rss, 0, NTOK * 4, stream);

    // QKV = x @ Wb^T + bias   [8192 x 1536], K=512
    gemm256<0, 4><<<dim3(QKVW / 256, NTOK / 256), 512, 0, stream>>>(
        xb, DIM, Wb, DIM, DIM, QKV, QKVW, bc, nullptr);

    // Vt[d][j] from QKV's V block
    transpose_v<<<dim3(NTOK / 64, DIM / 64), 256, 0, stream>>>(QKV, Vt);

    // S = Q @ K^T  [8192 x 8192], K=512 ; rowss += per-row sumsq
    gemm256<1, 4><<<dim3(NTOK / 256, NTOK / 256), 512, 0, stream>>>(
        QKV, QKVW, QKV + DIM, QKVW, DIM, S, NTOK, nullptr, rss);

    // O partials = S @ Vt^T, split-K=2  [8192 x 512]
    gemm256<2, 2><<<dim3(DIM / 128, NTOK / 256, 2), 512, 0, stream>>>(
        S, NTOK, Vt, NTOK, NTOK / 2, part, DIM, nullptr, nullptr);

    // out = (p0 + p1) * rsqrt(rowss)
    reduce_scale<<<NTOK * DIM / 4 / 256, 256, 0, stream>>>(part, rss, out);
}

// Round 3
// 308.988 us; speedup vs baseline: 1.1445x; 1.1445x over previous
//
#include <hip/hip_runtime.h>
#include <hip/hip_bf16.h>
#include <stdint.h>

#define NTOK 8192
#define DIM  512
#define QKVW 1536

typedef __attribute__((ext_vector_type(8))) short bf16x8;
typedef __attribute__((ext_vector_type(4))) float f32x4;

static __device__ __forceinline__ unsigned short f2b(float f) {
    union { float f; unsigned int u; } v; v.f = f;
    unsigned int r = v.u + 0x7fffu + ((v.u >> 16) & 1u);
    return (unsigned short)(r >> 16);
}

static __device__ __forceinline__ void gld_lds16(const void* g, void* l) {
    __builtin_amdgcn_global_load_lds(
        (__attribute__((address_space(1))) void*)(uintptr_t)g,
        (__attribute__((address_space(3))) void*)(uintptr_t)l,
        16, 0, 0);
}

#define SBAR() do { __builtin_amdgcn_sched_barrier(0); __builtin_amdgcn_s_barrier(); __builtin_amdgcn_sched_barrier(0); } while (0)

template <int N> static __device__ __forceinline__ void vmw() {
    __builtin_amdgcn_sched_barrier(0);
    if constexpr (N == 6)      asm volatile("s_waitcnt vmcnt(6)" ::: "memory");
    else                       asm volatile("s_waitcnt vmcnt(0)" ::: "memory");
    __builtin_amdgcn_sched_barrier(0);
}

// ---------------- converts ----------------

__global__ void f2b_kernel(const float* __restrict__ src, unsigned short* __restrict__ dst, int n4) {
    int i = blockIdx.x * blockDim.x + threadIdx.x;
    if (i < n4) {
        float4 f = ((const float4*)src)[i];
        ushort4 o;
        o.x = f2b(f.x); o.y = f2b(f.y); o.z = f2b(f.z); o.w = f2b(f.w);
        ((ushort4*)dst)[i] = o;
    }
}

__global__ void bias_concat(const float* __restrict__ bq, const float* __restrict__ bk,
                            const float* __restrict__ bv, float* __restrict__ bc) {
    int i = blockIdx.x * blockDim.x + threadIdx.x;
    if (i < 512)       bc[i] = bq[i];
    else if (i < 1024) bc[i] = bk[i - 512];
    else if (i < 1536) bc[i] = bv[i - 1024];
}

// ---------------- V transpose ----------------
__global__ void transpose_v(const unsigned short* __restrict__ qkv, unsigned short* __restrict__ vt) {
    __shared__ unsigned short t[64][65];
    int j0 = blockIdx.x * 64;
    int d0 = blockIdx.y * 64;
    int tid = threadIdx.x;
    int c  = tid & 63;
    int r4 = tid >> 6;
    #pragma unroll
    for (int r = r4; r < 64; r += 4)
        t[r][c] = qkv[(size_t)(j0 + r) * QKVW + 1024 + d0 + c];
    __syncthreads();
    #pragma unroll
    for (int r = r4; r < 64; r += 4)
        vt[(size_t)(d0 + r) * NTOK + j0 + c] = t[c][r];
}

// ---------------- 8-phase 256x256 GEMM, C = A * B^T ----------------
// BM=BN=256, BK=64, 8 waves (2Mx4N), per-wave 128x64 out, acc[8][4].
// LDS 128KB: 2 bufs x (A 32KB + B 32KB), blocked [chunk 0-7][row 0-255][16B],
// chunk = kk*4 + (lane>>4). Staged via linear-dest gld_lds + pre-permuted src.
// Per K-tile: 4 phases {ds_read || 1 half-tile stage -> bar -> 16 MFMA -> bar}.
// Stage slots (iter i): ph0: T1.B1 | ph1: T2.A0 | ph2: T2.A1 | ph3: T2.B0 +vm6
//                       ph4: T2.B1 | ph5: T3.A0 | ph6: T3.A1 | ph7: T3.B0 +vm6
// (T1=2i+1 buf1, T2=2i+2 buf0, T3=2i+3 buf1; every slot >=1 phase after the
//  target region's last ds_read; vmcnt(6) => all but 3 newest halves landed.)
template <int EPI>
__global__ __launch_bounds__(512, 2) void gemm8p(
    const unsigned short* __restrict__ A, int lda,
    const unsigned short* __restrict__ B, int ldb,
    int Ksplit,
    void* __restrict__ Cout, int ldc,
    const float* __restrict__ bias,
    float* __restrict__ rowss) {

    __shared__ __align__(16) char lds[131072];

    const int tid = threadIdx.x;
    const int l = tid & 63, w = tid >> 6;
    const int wm = w >> 2, wn = w & 3;

    // bijective XCD swizzle (x*y divisible by 8 for all launches)
    const int gx = gridDim.x;
    const int bid = blockIdx.y * gx + blockIdx.x;
    const int cpx = (gridDim.y * gx) >> 3;
    const int swz = (bid & 7) * cpx + (bid >> 3);
    const int bn = swz % gx, bm = swz / gx;

    const int kt0 = blockIdx.z * Ksplit;
    const int NT = Ksplit >> 6;
    const int NI = NT >> 1;

    const unsigned short* gA0 = A + (size_t)(bm * 256 + (w & 1) * 64 + l) * lda + kt0 + (w >> 1) * 8;
    const unsigned short* gB0 = B + (size_t)(bn * 256 + (w & 1) * 64 + l) * ldb + kt0 + (w >> 1) * 8;

    auto STG_A = [&](int buf, int t, int h) {
        const unsigned short* g = gA0 + (size_t)h * 128 * lda + t * 64;
        char* d = lds + buf * 65536 + (w >> 1) * 4096 + h * 2048 + (w & 1) * 1024;
        gld_lds16(g, d);
        gld_lds16(g + 32, d + 16384);
    };
    auto STG_B = [&](int buf, int t, int h) {
        const unsigned short* g = gB0 + (size_t)h * 128 * ldb + t * 64;
        char* d = lds + buf * 65536 + 32768 + (w >> 1) * 4096 + h * 2048 + (w & 1) * 1024;
        gld_lds16(g, d);
        gld_lds16(g + 32, d + 16384);
    };

    f32x4 acc[8][4] = {};
    bf16x8 af[8][2], bf[4][2];

    const int lrdA = (l >> 4) * 4096 + ((l & 15) + wm * 128) * 16;
    const int lrdB = 32768 + (l >> 4) * 4096 + ((l & 15) + wn * 64) * 16;

    auto RD_AF = [&](int buf) {
        const char* lb = lds + buf * 65536;
        #pragma unroll
        for (int m = 0; m < 8; ++m) {
            af[m][0] = *(const bf16x8*)(lb + lrdA + m * 256);
            af[m][1] = *(const bf16x8*)(lb + lrdA + m * 256 + 16384);
        }
    };
    auto RD_BF = [&](int buf, int j) {
        const char* lb = lds + buf * 65536;
        bf[j][0] = *(const bf16x8*)(lb + lrdB + j * 256);
        bf[j][1] = *(const bf16x8*)(lb + lrdB + j * 256 + 16384);
    };
    auto MM = [&](int j) {
        __builtin_amdgcn_s_setprio(1);
        #pragma unroll
        for (int m = 0; m < 8; ++m) {
            acc[m][j] = __builtin_amdgcn_mfma_f32_16x16x32_bf16(af[m][0], bf[j][0], acc[m][j], 0, 0, 0);
            acc[m][j] = __builtin_amdgcn_mfma_f32_16x16x32_bf16(af[m][1], bf[j][1], acc[m][j], 0, 0, 0);
        }
        __builtin_amdgcn_s_setprio(0);
    };

    // prologue: tile0 fully, tile1 A0,A1,B0 (7 halves); wait tile0 landed.
    STG_A(0, 0, 0); STG_A(0, 0, 1); STG_B(0, 0, 0); STG_B(0, 0, 1);
    STG_A(1, 1, 0); STG_A(1, 1, 1); STG_B(1, 1, 0);
    vmw<6>();
    SBAR();

    for (int i = 0; i < NI; ++i) {
        const bool st = (i + 1 < NI);
        const int T2 = 2 * i + 2, T3 = 2 * i + 3;
        // ---- buf0 = tile 2i ----
        RD_AF(0); RD_BF(0, 0); RD_BF(0, 1);
        STG_B(1, 2 * i + 1, 1);
        SBAR(); MM(0); SBAR();

        RD_BF(0, 2);
        if (st) STG_A(0, T2, 0);
        SBAR(); MM(1); SBAR();

        RD_BF(0, 3);
        if (st) STG_A(0, T2, 1);
        SBAR(); MM(2); SBAR();

        if (st) { STG_B(0, T2, 0); vmw<6>(); } else vmw<0>();
        SBAR(); MM(3); SBAR();

        // ---- buf1 = tile 2i+1 ----
        RD_AF(1); RD_BF(1, 0); RD_BF(1, 1);
        if (st) STG_B(0, T2, 1);
        SBAR(); MM(0); SBAR();

        RD_BF(1, 2);
        if (st) STG_A(1, T3, 0);
        SBAR(); MM(1); SBAR();

        RD_BF(1, 3);
        if (st) STG_A(1, T3, 1);
        SBAR(); MM(2); SBAR();

        if (st) { STG_B(1, T3, 0); vmw<6>(); }
        SBAR(); MM(3); SBAR();
    }

    const int rbase = bm * 256 + wm * 128 + (l >> 4) * 4;
    const int cbase = bn * 256 + wn * 64 + (l & 15);

    if constexpr (EPI == 0) {
        unsigned short* C = (unsigned short*)Cout;
        #pragma unroll
        for (int m = 0; m < 8; ++m)
            #pragma unroll
            for (int n = 0; n < 4; ++n)
                #pragma unroll
                for (int j = 0; j < 4; ++j) {
                    int r = rbase + m * 16 + j;
                    int c = cbase + n * 16;
                    C[(size_t)r * ldc + c] = f2b(acc[m][n][j] + bias[c]);
                }
    } else if constexpr (EPI == 1) {
        unsigned short* C = (unsigned short*)Cout;
        #pragma unroll
        for (int m = 0; m < 8; ++m)
            #pragma unroll
            for (int n = 0; n < 4; ++n)
                #pragma unroll
                for (int j = 0; j < 4; ++j) {
                    int r = rbase + m * 16 + j;
                    int c = cbase + n * 16;
                    C[(size_t)r * ldc + c] = f2b(acc[m][n][j]);
                }
        #pragma unroll
        for (int m = 0; m < 8; ++m)
            #pragma unroll
            for (int j = 0; j < 4; ++j) {
                float p = 0.f;
                #pragma unroll
                for (int n = 0; n < 4; ++n) {
                    float v = acc[m][n][j];
                    p += v * v;
                }
                p += __shfl_xor(p, 1);
                p += __shfl_xor(p, 2);
                p += __shfl_xor(p, 4);
                p += __shfl_xor(p, 8);
                if ((l & 15) == 0)
                    atomicAdd(&rowss[rbase + m * 16 + j], p);
            }
    } else {
        float* C = (float*)Cout + (size_t)blockIdx.z * NTOK * ldc;
        #pragma unroll
        for (int m = 0; m < 8; ++m)
            #pragma unroll
            for (int j = 0; j < 4; ++j) {
                int r = rbase + m * 16 + j;
                #pragma unroll
                for (int n = 0; n < 4; ++n)
                    C[(size_t)r * ldc + cbase + n * 16] = acc[m][n][j];
            }
    }
}

// ---------------- split-K reduce + row-norm scale ----------------
__global__ void reduce_scale(const float* __restrict__ p, const float* __restrict__ rss,
                             float* __restrict__ out) {
    int i = blockIdx.x * blockDim.x + threadIdx.x;  // over NTOK*DIM/4
    const size_t stride = (size_t)NTOK * DIM / 4;
    float4 a = ((const float4*)p)[i];
    const float4 b = ((const float4*)p)[i + stride];
    const float4 c = ((const float4*)p)[i + 2 * stride];
    const float4 d = ((const float4*)p)[i + 3 * stride];
    int r = (i << 2) >> 9;  // (i*4)/DIM
    float s = 1.0f / fmaxf(sqrtf(rss[r]), 1e-12f);
    float4 o;
    o.x = (a.x + b.x + c.x + d.x) * s;
    o.y = (a.y + b.y + c.y + d.y) * s;
    o.z = (a.z + b.z + c.z + d.z) * s;
    o.w = (a.w + b.w + c.w + d.w) * s;
    ((float4*)out)[i] = o;
}

extern "C" void kernel_launch(void* const* d_in, const int* in_sizes, int n_in,
                              void* d_out, int out_size, void* d_ws, size_t ws_size,
                              hipStream_t stream) {
    const float* x  = (const float*)d_in[0];
    const float* Wq = (const float*)d_in[1];
    const float* bq = (const float*)d_in[2];
    const float* Wk = (const float*)d_in[3];
    const float* bk = (const float*)d_in[4];
    const float* Wv = (const float*)d_in[5];
    const float* bv = (const float*)d_in[6];
    float* out = (float*)d_out;

    char* ws = (char*)d_ws;
    size_t off = 0;
    auto alloc = [&](size_t bytes) -> void* {
        void* p = ws + off;
        off = (off + bytes + 255) & ~(size_t)255;
        return p;
    };

    unsigned short* xb   = (unsigned short*)alloc((size_t)NTOK * DIM * 2);
    unsigned short* Wb   = (unsigned short*)alloc((size_t)QKVW * DIM * 2);
    float*          bc   = (float*)alloc(QKVW * 4);
    unsigned short* QKV  = (unsigned short*)alloc((size_t)NTOK * QKVW * 2);
    unsigned short* Vt   = (unsigned short*)alloc((size_t)DIM * NTOK * 2);
    float*          rss  = (float*)alloc(NTOK * 4);
    float*          part = (float*)alloc((size_t)4 * NTOK * DIM * 4);
    unsigned short* S    = (unsigned short*)alloc((size_t)NTOK * NTOK * 2);

    // converts
    f2b_kernel<<<(NTOK * DIM / 4 + 255) / 256, 256, 0, stream>>>(x, xb, NTOK * DIM / 4);
    f2b_kernel<<<(DIM * DIM / 4 + 255) / 256, 256, 0, stream>>>(Wq, Wb, DIM * DIM / 4);
    f2b_kernel<<<(DIM * DIM / 4 + 255) / 256, 256, 0, stream>>>(Wk, Wb + DIM * DIM, DIM * DIM / 4);
    f2b_kernel<<<(DIM * DIM / 4 + 255) / 256, 256, 0, stream>>>(Wv, Wb + 2 * DIM * DIM, DIM * DIM / 4);
    bias_concat<<<6, 256, 0, stream>>>(bq, bk, bv, bc);
    hipMemsetAsync(rss, 0, NTOK * 4, stream);

    // QKV = x @ Wb^T + bias   [8192 x 1536], K=512
    gemm8p<0><<<dim3(QKVW / 256, NTOK / 256), 512, 0, stream>>>(
        xb, DIM, Wb, DIM, DIM, QKV, QKVW, bc, nullptr);

    // Vt[d][j] from QKV's V block
    transpose_v<<<dim3(NTOK / 64, DIM / 64), 256, 0, stream>>>(QKV, Vt);

    // S = Q @ K^T  [8192 x 8192], K=512 ; rowss += per-row sumsq
    gemm8p<1><<<dim3(NTOK / 256, NTOK / 256), 512, 0, stream>>>(
        QKV, QKVW, QKV + DIM, QKVW, DIM, S, NTOK, nullptr, rss);

    // O partials = S @ Vt^T, split-K=4  [8192 x 512]
    gemm8p<2><<<dim3(DIM / 256, NTOK / 256, 4), 512, 0, stream>>>(
        S, NTOK, Vt, NTOK, NTOK / 4, part, DIM, nullptr, nullptr);

    // out = (p0+p1+p2+p3) * rsqrt(rowss)
    reduce_scale<<<NTOK * DIM / 4 / 256, 256, 0, stream>>>(part, rss, out);
}